// Round 1
// baseline (327.579 us; speedup 1.0000x reference)
//
#include <hip/hip_runtime.h>
#include <math.h>

// Sampler: temperature 0.8, top-k (k=50 input), top-p 0.9, inverse-CDF
// multinomial. B=128 rows, V=128000, fp32 logits -> int32 ids.
//
// R12: fused single-kernel version of R11. The 2048 scan blocks (16 slices
// x 128 rows) keep R10's interleaved 8x-float4 MLP scan. Handoff: each
// block release-fences its candidate segment and tickets done[row]; the
// 16th (last) arriver acquires and runs the per-row selection in-place
// with 256 threads (wave-0 barrier-free tail unchanged from R11). This
// removes the select_kernel launch + the device-wide inter-kernel boundary.
//  - tickets zeroed by a 512 B hipMemsetAsync (ws is poisoned per iter).
//  - ONE global atomic + 2 fences per block, at block END only (R2/R5
//    lessons were hot-path costs; this is cold epilogue).
//  - slow tail (Kp > 128 / M == 0; never fires on this data) rewritten
//    serial-exact on thread 0; block_sum/incl_scan dropped -> select LDS
//    16.5 KB so every block still fits >=7/CU during the scan phase.
//  - exact fallback (segment overflow / total < k) kept, ported to 256 thr.

#define SLICES   16
#define SEGCAP   64
#define MSORT    1024
#define NTH      256

__device__ __forceinline__ unsigned fkey(float y) {
    unsigned b = __float_as_uint(y);
    return (b & 0x80000000u) ? ~b : (b | 0x80000000u);  // y asc -> key asc
}

// wave-wide (64-lane) helpers, no barriers
__device__ __forceinline__ float wsum(float v) {
#pragma unroll
    for (int off = 32; off > 0; off >>= 1) v += __shfl_xor(v, off, 64);
    return v;
}
__device__ __forceinline__ float wscan(float v, int lane) {
#pragma unroll
    for (int off = 1; off < 64; off <<= 1) {
        float o = __shfl_up(v, off, 64);
        if (lane >= off) v += o;
    }
    return v;
}

__global__ __launch_bounds__(256)
void fused_kernel(const float* __restrict__ logits,
                  const float* __restrict__ uvec,
                  const int* __restrict__ topk_p,
                  int* __restrict__ done_ctr,
                  int* __restrict__ scnt,
                  float* __restrict__ cy, int* __restrict__ ci,
                  int* __restrict__ out, int V)
{
    constexpr float YTH  = 11.2f;   // x = 14.0
    constexpr float TEMP = 0.8f;
    constexpr float TOPP = 0.9f;
    constexpr float XTH2 = 16.0f;   // two-tier threshold in x-space

    // Sv/Si: rank-sorted candidates. Av/Ai: pre-sort candidates (and, in the
    // scan phase, the first 64 entries double as the slice-local lcy/lci;
    // in the fast tail they hold the vocab-order prob/idx scatter).
    __shared__ float Sv[MSORT];
    __shared__ int   Si[MSORT];
    __shared__ float Av[MSORT];
    __shared__ int   Ai[MSORT];
    __shared__ int   segoff[SLICES + 1];
    __shared__ int   lcnt, is_last_sh;
    __shared__ int   hi_cnt, cpos, scount, cnt_sh, M_sh, Kp_sh, fast_sh, bad_sh;

    const int tid  = threadIdx.x;
    const int lane = tid & 63;
    const int row  = blockIdx.x / SLICES;
    const int sl   = blockIdx.x % SLICES;

    if (tid == 0) lcnt = 0;
    __syncthreads();

    const float* rowp = logits + (size_t)row * (size_t)V;
    const float4* rp4 = (const float4*)rowp;
    const int n4   = V >> 2;
    const int base = sl * 256 + tid;    // float4 index, stride 4096 per j

#define PUSH4(vv, i4)                                                            \
    {                                                                            \
        float _m = fmaxf(fmaxf((vv).x, (vv).y), fmaxf((vv).z, (vv).w));          \
        if (_m >= YTH) {                                                         \
            if ((vv).x >= YTH) { int _p = atomicAdd(&lcnt, 1);                   \
                if (_p < SEGCAP) { Av[_p] = (vv).x; Ai[_p] = (i4) * 4;     } }   \
            if ((vv).y >= YTH) { int _p = atomicAdd(&lcnt, 1);                   \
                if (_p < SEGCAP) { Av[_p] = (vv).y; Ai[_p] = (i4) * 4 + 1; } }   \
            if ((vv).z >= YTH) { int _p = atomicAdd(&lcnt, 1);                   \
                if (_p < SEGCAP) { Av[_p] = (vv).z; Ai[_p] = (i4) * 4 + 2; } }   \
            if ((vv).w >= YTH) { int _p = atomicAdd(&lcnt, 1);                   \
                if (_p < SEGCAP) { Av[_p] = (vv).w; Ai[_p] = (i4) * 4 + 3; } }   \
        }                                                                        \
    }

    if (sl * 256 + 255 + 7 * 4096 < n4) {
        // fast path: 8 unconditional back-to-back loads (full MLP)
        float4 a0 = rp4[base];
        float4 a1 = rp4[base + 4096];
        float4 a2 = rp4[base + 8192];
        float4 a3 = rp4[base + 12288];
        float4 a4 = rp4[base + 16384];
        float4 a5 = rp4[base + 20480];
        float4 a6 = rp4[base + 24576];
        float4 a7 = rp4[base + 28672];
        PUSH4(a0, base);
        PUSH4(a1, base + 4096);
        PUSH4(a2, base + 8192);
        PUSH4(a3, base + 12288);
        PUSH4(a4, base + 16384);
        PUSH4(a5, base + 20480);
        PUSH4(a6, base + 24576);
        PUSH4(a7, base + 28672);
    } else {
        // edge slices: clamped branch-free loads, validity-flagged pushes
        const int nc = n4 - 1;
        int i0 = base,          c0 = min(i0, nc);
        int i1 = base + 4096,   c1 = min(i1, nc);
        int i2 = base + 8192,   c2 = min(i2, nc);
        int i3 = base + 12288,  c3 = min(i3, nc);
        int i4_ = base + 16384, c4 = min(i4_, nc);
        int i5 = base + 20480,  c5 = min(i5, nc);
        int i6 = base + 24576,  c6 = min(i6, nc);
        int i7 = base + 28672,  c7 = min(i7, nc);
        float4 a0 = rp4[c0];
        float4 a1 = rp4[c1];
        float4 a2 = rp4[c2];
        float4 a3 = rp4[c3];
        float4 a4 = rp4[c4];
        float4 a5 = rp4[c5];
        float4 a6 = rp4[c6];
        float4 a7 = rp4[c7];
        if (i0 < n4) PUSH4(a0, i0);
        if (i1 < n4) PUSH4(a1, i1);
        if (i2 < n4) PUSH4(a2, i2);
        if (i3 < n4) PUSH4(a3, i3);
        if (i4_ < n4) PUSH4(a4, i4_);
        if (i5 < n4) PUSH4(a5, i5);
        if (i6 < n4) PUSH4(a6, i6);
        if (i7 < n4) PUSH4(a7, i7);
    }
    // general-V coverage beyond 32768 float4/row (empty for V=128000)
    for (int i = SLICES * 256 * 8 + sl * 256 + tid; i < n4; i += SLICES * 256) {
        float4 a = rp4[i];
        PUSH4(a, i);
    }
    if (sl == SLICES - 1) {   // scalar tail if V % 4 != 0
        for (int i = (n4 << 2) + tid; i < V; i += 256) {
            float y = rowp[i];
            if (y >= YTH) {
                int p = atomicAdd(&lcnt, 1);
                if (p < SEGCAP) { Av[p] = y; Ai[p] = i; }
            }
        }
    }
#undef PUSH4
    __syncthreads();

    const int cnt = lcnt;
    {
        float* cyr = cy + ((size_t)row * SLICES + sl) * SEGCAP;
        int*   cir = ci + ((size_t)row * SLICES + sl) * SEGCAP;
        for (int p = tid; p < min(cnt, SEGCAP); p += NTH) {
            cyr[p] = Av[p];
            cir[p] = Ai[p];
        }
        if (tid == 0) scnt[row * SLICES + sl] = cnt;  // cnt > SEGCAP => overflow
    }

    // ---- handoff: last-arriving block of this row runs the selection ----
    __threadfence();                 // release: publish segment to device scope
    __syncthreads();                 // (syncthreads also drains vmcnt)
    if (tid == 0)
        is_last_sh = (atomicAdd(&done_ctr[row], 1) == SLICES - 1);
    __syncthreads();
    if (!is_last_sh) return;         // block-uniform
    __threadfence();                 // acquire: see all 16 slices' data

    // ================= selection phase (256 threads) =================
    const int k_in = *topk_p;

    if (tid == 0) { hi_cnt = 0; cpos = 0; scount = 0; }
    if (tid < 64) {
        int c = (tid < SLICES) ? scnt[row * SLICES + tid] : 0;
        int bad = (tid < SLICES) && (c > SEGCAP);
        int acc = min(c, SEGCAP);
#pragma unroll
        for (int off = 1; off < SLICES; off <<= 1) {
            int o = __shfl_up(acc, off, 64);
            if (tid >= off) acc += o;
        }
        if (tid < SLICES) segoff[tid + 1] = acc;
        if (tid == 0) segoff[0] = 0;
        unsigned long long bm = __ballot(bad);
        if (tid == 0) bad_sh = (bm != 0ULL);
    }
    __syncthreads();

    const int M_all = segoff[SLICES];
    int M;
    if (!bad_sh && M_all >= k_in && M_all <= MSORT) {
        {   // stage candidates: wave wv handles segments wv, wv+4, wv+8, wv+12
            const int wv = tid >> 6;
            for (int s = wv; s < SLICES; s += 4) {
                const int off = segoff[s];
                const int c   = segoff[s + 1] - off;
                if (lane < c) {
                    const size_t gbase = ((size_t)row * SLICES + s) * SEGCAP + lane;
                    Sv[off + lane] = cy[gbase] / TEMP;
                    Si[off + lane] = ci[gbase];
                }
            }
        }
        __syncthreads();
        {   // count high-tier candidates
            const int rounds = (M_all + NTH - 1) / NTH;
            for (int rd = 0; rd < rounds; ++rd) {
                const int t = rd * NTH + tid;
                bool pred = (t < M_all) && (Sv[t] >= XTH2);
                unsigned long long bm = __ballot(pred);
                if (lane == 0 && bm) atomicAdd(&hi_cnt, (int)__popcll(bm));
            }
        }
        __syncthreads();
        const float thr = (hi_cnt >= k_in) ? XTH2 : -1e38f;
        {   // compact survivors into Av/Ai (order canonicalized by rank sort)
            const int rounds = (M_all + NTH - 1) / NTH;
            for (int rd = 0; rd < rounds; ++rd) {
                const int t = rd * NTH + tid;
                bool pred = (t < M_all) && (Sv[t] >= thr);
                unsigned long long bm = __ballot(pred);
                if (bm) {
                    int fl = (int)__ffsll(bm) - 1;
                    int bs = 0;
                    if (pred && lane == fl) bs = atomicAdd(&cpos, (int)__popcll(bm));
                    bs = __shfl(bs, fl, 64);
                    if (pred) {
                        int p = bs + (int)__popcll(bm & ((1ULL << lane) - 1ULL));
                        Av[p] = Sv[t]; Ai[p] = Si[t];
                    }
                }
            }
        }
        __syncthreads();
        M = cpos;
    } else {
        // exact fallback: kth value via binary search on float key bits
        unsigned lo = 0;
        for (int bit = 31; bit >= 0; --bit) {
            unsigned tb = lo | (1u << bit);
            int local = 0;
            for (int i = tid; i < V; i += NTH) local += (fkey(rowp[i]) >= tb);
            if (tid == 0) cnt_sh = 0;
            __syncthreads();
            atomicAdd(&cnt_sh, local);
            __syncthreads();
            if (cnt_sh >= k_in) lo = tb;
            __syncthreads();
        }
        for (int i = tid; i < V; i += NTH) {
            float y = rowp[i];
            if (fkey(y) >= lo) {
                int p = atomicAdd(&scount, 1);
                if (p < MSORT) { Av[p] = y / TEMP; Ai[p] = i; }
            }
        }
        __syncthreads();
        M = min(scount, MSORT);
    }
    if (tid == 0) M_sh = M;
    __syncthreads();
    M = M_sh;

    // pad to multiple of 4 with sentinels (branch-free unrolled inner loop)
    const int Mpad = (M + 3) & ~3;
    for (int t = M + tid; t < Mpad; t += NTH) { Av[t] = -1e38f; Ai[t] = 0x7fffffff; }
    __syncthreads();

    // rank sort: x desc, tie idx asc (== argsort(-x)); writes into Sv/Si
    for (int t = tid; t < M; t += NTH) {
        const float v = Av[t]; const int ix = Ai[t];
        int r = 0;
        for (int j = 0; j < Mpad; j += 4) {
            float v0 = Av[j],     v1 = Av[j + 1];
            float v2 = Av[j + 2], v3 = Av[j + 3];
            int   i0 = Ai[j],     i1 = Ai[j + 1];
            int   i2 = Ai[j + 2], i3 = Ai[j + 3];
            r += (v0 > v || (v0 == v && i0 < ix));
            r += (v1 > v || (v1 == v && i1 < ix));
            r += (v2 > v || (v2 == v && i2 < ix));
            r += (v3 > v || (v3 == v && i3 < ix));
        }
        Sv[r] = v; Si[r] = ix;
    }
    __syncthreads();

    // ---- decide fast (wave-0, Kp <= 128) vs slow tail ----
    if (tid < 64) {
        int kk = (M > 0) ? min(max(k_in, 1), M) : 0;
        float kth = (M > 0) ? Sv[kk - 1] : 0.0f;
        int j0 = min(kk + lane, MSORT - 1);
        int j1 = min(kk + 64 + lane, MSORT - 1);
        bool t0 = (M > 0) && (kk + lane < M)      && (Sv[j0] == kth);
        bool t1 = (M > 0) && (kk + 64 + lane < M) && (Sv[j1] == kth);
        int cnt2 = (int)__popcll(__ballot(t0)) + (int)__popcll(__ballot(t1));
        if (lane == 0) {
            Kp_sh = kk + cnt2;
            fast_sh = (M > 0) && (Kp_sh <= 128);
        }
    }
    __syncthreads();

    if (fast_sh) {
        // ================= wave-0 barrier-free tail (verbatim R11) ==========
        if (tid < 64) {
            const int Kp = Kp_sh;
            const int e0 = lane, e1 = lane + 64;
            const float mm = Sv[0];
            float se0 = (e0 < Kp) ? expf(Sv[e0] - mm) : 0.0f;
            float se1 = (e1 < Kp) ? expf(Sv[e1] - mm) : 0.0f;

            const float sum1 = wsum(se0 + se1);
            float q0 = se0 / sum1, q1 = se1 / sum1;

            // inclusive cdf over element order [0..Kp)
            float s0 = wscan(q0, lane);
            float T0 = __shfl(s0, 63, 64);
            float s1 = wscan(q1, lane) + T0;

            float prev0 = __shfl_up(s0, 1, 64);                 // Q[e0-1]
            float prev1 = __shfl_up(s1, 1, 64);
            if (lane == 0) prev1 = T0;                          // Q[63]
            bool c0 = (e0 >= 1) && (e0 < Kp) && (prev0 <= TOPP);
            bool c1 = (e1 < Kp) && (prev1 <= TOPP);
            const int L = 1 + (int)__popcll(__ballot(c0)) + (int)__popcll(__ballot(c1));

            const float sum2 = wsum(((e0 < L) ? se0 : 0.0f) + ((e1 < L) ? se1 : 0.0f));
            float p0 = se0 / sum2, p1 = se1 / sum2;
            int i0 = (e0 < L) ? Si[e0] : 0x7fffffff;
            int i1 = (e1 < L) ? Si[e1] : 0x7fffffff;

            // pad Si[L..Lpad) with INT_MAX for the x4-unrolled rank loop
            const int Lpad = (L + 3) & ~3;
            if (lane < Lpad - L) Si[L + lane] = 0x7fffffff;
            __builtin_amdgcn_wave_barrier();

            int r0 = 0, r1 = 0;
            for (int j = 0; j < Lpad; j += 4) {
                int g0 = Si[j], g1 = Si[j + 1], g2 = Si[j + 2], g3 = Si[j + 3];
                r0 += (g0 < i0) + (g1 < i0) + (g2 < i0) + (g3 < i0);
                r1 += (g0 < i1) + (g1 < i1) + (g2 < i1) + (g3 < i1);
            }
            if (e0 < L) { Av[r0] = p0; Ai[r0] = i0; }
            if (e1 < L) { Av[r1] = p1; Ai[r1] = i1; }
            __builtin_amdgcn_wave_barrier();

            // vocab-order cdf + unique crossing
            float g0v = (e0 < L) ? Av[e0] : 0.0f;
            float g1v = (e1 < L) ? Av[e1] : 0.0f;
            int   vi0 = (e0 < L) ? Ai[e0] : 0;
            int   vi1 = (e1 < L) ? Ai[e1] : 0;
            float C0 = wscan(g0v, lane);
            float TT = __shfl(C0, 63, 64);
            float C1 = wscan(g1v, lane) + TT;
            float pc0 = __shfl_up(C0, 1, 64);
            float pc1 = __shfl_up(C1, 1, 64);
            if (lane == 0) pc1 = TT;
            const float uu = uvec[row];
            bool f0 = (e0 < L) && (C0 > uu) && (e0 == 0 || pc0 <= uu);
            bool f1 = (e1 < L) && (C1 > uu) && (pc1 <= uu);
            int ans = V;
            if (f0) ans = vi0;
            if (f1) ans = vi1;
#pragma unroll
            for (int off = 32; off > 0; off >>= 1)
                ans = min(ans, __shfl_xor(ans, off, 64));
            if (lane == 0) out[row] = ans;
        }
        return;
    }

    // ============ slow tail (Kp > 128 / M == 0): serial-exact, never fires ==
    if (tid == 0) {
        int ans = V;
        if (M > 0) {
            const int kk = min(max(k_in, 1), M);
            const float kth = Sv[kk - 1];
            int Kp = kk;
            for (int t = kk; t < M; ++t) Kp += (Sv[t] == kth);
            const float mm = Sv[0];
            float sum1 = 0.0f;
            for (int t = 0; t < Kp; ++t) sum1 += expf(Sv[t] - mm);
            // L = 1 + #{ t in [1,Kp) : cdf[t-1] <= TOPP }
            int L = 1;
            float pref = 0.0f;
            for (int t = 1; t < Kp; ++t) {
                pref += expf(Sv[t - 1] - mm) / sum1;
                L += (pref <= TOPP);
            }
            float sum2 = 0.0f;
            for (int t = 0; t < L; ++t) sum2 += expf(Sv[t] - mm);
            const float uu = uvec[row];
            // vocab-order traversal via repeated min-extraction; first cdf>u
            int last = -1;
            float csum = 0.0f;
            for (int step = 0; step < L; ++step) {
                int mn = 0x7fffffff, mt = -1;
                for (int t = 0; t < L; ++t) {
                    int ix = Si[t];
                    if (ix > last && ix < mn) { mn = ix; mt = t; }
                }
                last = mn;
                csum += expf(Sv[mt] - mm) / sum2;
                if (csum > uu) { ans = mn; break; }
            }
        }
        out[row] = ans;
    }
}

extern "C" void kernel_launch(void* const* d_in, const int* in_sizes, int n_in,
                              void* d_out, int out_size, void* d_ws, size_t ws_size,
                              hipStream_t stream) {
    const float* logits = (const float*)d_in[0];
    const float* u      = (const float*)d_in[1];
    const int*   topk   = (const int*)d_in[2];
    int*         out    = (int*)d_out;

    const int B = out_size;              // 128 rows
    const int V = in_sizes[0] / B;       // 128000

    // ws layout: done[B] | scnt[B*SLICES] | cy[B*SLICES*SEGCAP f32] | ci[i32]
    const size_t n_scnt = (size_t)B * SLICES;
    const size_t n_seg  = (size_t)B * SLICES * SEGCAP;
    int*   done = (int*)d_ws;
    int*   scnt = done + B;
    float* cy   = (float*)(scnt + n_scnt);
    int*   ci   = (int*)(cy + n_seg);

    (void)hipMemsetAsync(done, 0, (size_t)B * sizeof(int), stream);
    fused_kernel<<<B * SLICES, NTH, 0, stream>>>(logits, u, topk,
                                                 done, scnt, cy, ci, out, V);
}

// Round 2
// 107.739 us; speedup vs baseline: 3.0405x; 3.0405x over previous
//
#include <hip/hip_runtime.h>
#include <math.h>

// Sampler: temperature 0.8, top-k (k=50 input), top-p 0.9, inverse-CDF
// multinomial. B=128 rows, V=128000, fp32 logits -> int32 ids.
//
// R13: fenceless fused kernel. R12's fusion was correct but its handoff used
// __threadfence(), which on multi-XCD gfx950 emits buffer_wbl2/buffer_inv
// (full 4 MiB L2 writeback/invalidate) -- 2048 of those serialized at the
// per-XCD L2s = ~290 us of parked waves (R12 counters: VALUBusy 0.7%,
// occupancy 62%, 105 GB/s). Fix: the handoff data is tiny, so move IT to the
// device coherence point instead of flushing L2 around it:
//  - producers write cy/ci/scnt with __hip_atomic_store(RELAXED, AGENT)
//    -> global_store ... sc1 (bypasses the non-coherent L2; no wbl2).
//  - __syncthreads() drains vmcnt(0): all sc1 stores ACKed at the coherence
//    point BEFORE tid0 issues the RELAXED sc1 ticket fetch_add.
//  - consumer (16th arriver per row) reads ticket, crosses a barrier, then
//    reads cy/ci/scnt with __hip_atomic_load(RELAXED, AGENT) (sc1 loads,
//    skip stale L1/L2). No fence anywhere; RELAXED only (ACQ_REL RMW would
//    re-emit wbl2/inv and recreate the storm).
//  - logits/u/topk are read-only (no coherence hazard); out is store-only
//    (end-of-kernel implicit release publishes it).
//  - tickets zeroed by a 512 B hipMemsetAsync (ws is poisoned per iter);
//    fill kernels end with an implicit release, so the zeros are visible.
// Selection phase (256 threads, wave-0 barrier-free tail) unchanged from R12.

#define SLICES   16
#define SEGCAP   64
#define MSORT    1024
#define NTH      256

#define ST_SC1(p, v) __hip_atomic_store((p), (v), __ATOMIC_RELAXED, __HIP_MEMORY_SCOPE_AGENT)
#define LD_SC1(p)    __hip_atomic_load((p), __ATOMIC_RELAXED, __HIP_MEMORY_SCOPE_AGENT)

__device__ __forceinline__ unsigned fkey(float y) {
    unsigned b = __float_as_uint(y);
    return (b & 0x80000000u) ? ~b : (b | 0x80000000u);  // y asc -> key asc
}

// wave-wide (64-lane) helpers, no barriers
__device__ __forceinline__ float wsum(float v) {
#pragma unroll
    for (int off = 32; off > 0; off >>= 1) v += __shfl_xor(v, off, 64);
    return v;
}
__device__ __forceinline__ float wscan(float v, int lane) {
#pragma unroll
    for (int off = 1; off < 64; off <<= 1) {
        float o = __shfl_up(v, off, 64);
        if (lane >= off) v += o;
    }
    return v;
}

__global__ __launch_bounds__(256)
void fused_kernel(const float* __restrict__ logits,
                  const float* __restrict__ uvec,
                  const int* __restrict__ topk_p,
                  int* __restrict__ done_ctr,
                  int* __restrict__ scnt,
                  float* __restrict__ cy, int* __restrict__ ci,
                  int* __restrict__ out, int V)
{
    constexpr float YTH  = 11.2f;   // x = 14.0
    constexpr float TEMP = 0.8f;
    constexpr float TOPP = 0.9f;
    constexpr float XTH2 = 16.0f;   // two-tier threshold in x-space

    // Sv/Si: rank-sorted candidates. Av/Ai: pre-sort candidates (and, in the
    // scan phase, the first 64 entries double as the slice-local lcy/lci;
    // in the fast tail they hold the vocab-order prob/idx scatter).
    __shared__ float Sv[MSORT];
    __shared__ int   Si[MSORT];
    __shared__ float Av[MSORT];
    __shared__ int   Ai[MSORT];
    __shared__ int   segoff[SLICES + 1];
    __shared__ int   lcnt, is_last_sh;
    __shared__ int   hi_cnt, cpos, scount, cnt_sh, M_sh, Kp_sh, fast_sh, bad_sh;

    const int tid  = threadIdx.x;
    const int lane = tid & 63;
    const int row  = blockIdx.x / SLICES;
    const int sl   = blockIdx.x % SLICES;

    if (tid == 0) lcnt = 0;
    __syncthreads();

    const float* rowp = logits + (size_t)row * (size_t)V;
    const float4* rp4 = (const float4*)rowp;
    const int n4   = V >> 2;
    const int base = sl * 256 + tid;    // float4 index, stride 4096 per j

#define PUSH4(vv, i4)                                                            \
    {                                                                            \
        float _m = fmaxf(fmaxf((vv).x, (vv).y), fmaxf((vv).z, (vv).w));          \
        if (_m >= YTH) {                                                         \
            if ((vv).x >= YTH) { int _p = atomicAdd(&lcnt, 1);                   \
                if (_p < SEGCAP) { Av[_p] = (vv).x; Ai[_p] = (i4) * 4;     } }   \
            if ((vv).y >= YTH) { int _p = atomicAdd(&lcnt, 1);                   \
                if (_p < SEGCAP) { Av[_p] = (vv).y; Ai[_p] = (i4) * 4 + 1; } }   \
            if ((vv).z >= YTH) { int _p = atomicAdd(&lcnt, 1);                   \
                if (_p < SEGCAP) { Av[_p] = (vv).z; Ai[_p] = (i4) * 4 + 2; } }   \
            if ((vv).w >= YTH) { int _p = atomicAdd(&lcnt, 1);                   \
                if (_p < SEGCAP) { Av[_p] = (vv).w; Ai[_p] = (i4) * 4 + 3; } }   \
        }                                                                        \
    }

    if (sl * 256 + 255 + 7 * 4096 < n4) {
        // fast path: 8 unconditional back-to-back loads (full MLP)
        float4 a0 = rp4[base];
        float4 a1 = rp4[base + 4096];
        float4 a2 = rp4[base + 8192];
        float4 a3 = rp4[base + 12288];
        float4 a4 = rp4[base + 16384];
        float4 a5 = rp4[base + 20480];
        float4 a6 = rp4[base + 24576];
        float4 a7 = rp4[base + 28672];
        PUSH4(a0, base);
        PUSH4(a1, base + 4096);
        PUSH4(a2, base + 8192);
        PUSH4(a3, base + 12288);
        PUSH4(a4, base + 16384);
        PUSH4(a5, base + 20480);
        PUSH4(a6, base + 24576);
        PUSH4(a7, base + 28672);
    } else {
        // edge slices: clamped branch-free loads, validity-flagged pushes
        const int nc = n4 - 1;
        int i0 = base,          c0 = min(i0, nc);
        int i1 = base + 4096,   c1 = min(i1, nc);
        int i2 = base + 8192,   c2 = min(i2, nc);
        int i3 = base + 12288,  c3 = min(i3, nc);
        int i4_ = base + 16384, c4 = min(i4_, nc);
        int i5 = base + 20480,  c5 = min(i5, nc);
        int i6 = base + 24576,  c6 = min(i6, nc);
        int i7 = base + 28672,  c7 = min(i7, nc);
        float4 a0 = rp4[c0];
        float4 a1 = rp4[c1];
        float4 a2 = rp4[c2];
        float4 a3 = rp4[c3];
        float4 a4 = rp4[c4];
        float4 a5 = rp4[c5];
        float4 a6 = rp4[c6];
        float4 a7 = rp4[c7];
        if (i0 < n4) PUSH4(a0, i0);
        if (i1 < n4) PUSH4(a1, i1);
        if (i2 < n4) PUSH4(a2, i2);
        if (i3 < n4) PUSH4(a3, i3);
        if (i4_ < n4) PUSH4(a4, i4_);
        if (i5 < n4) PUSH4(a5, i5);
        if (i6 < n4) PUSH4(a6, i6);
        if (i7 < n4) PUSH4(a7, i7);
    }
    // general-V coverage beyond 32768 float4/row (empty for V=128000)
    for (int i = SLICES * 256 * 8 + sl * 256 + tid; i < n4; i += SLICES * 256) {
        float4 a = rp4[i];
        PUSH4(a, i);
    }
    if (sl == SLICES - 1) {   // scalar tail if V % 4 != 0
        for (int i = (n4 << 2) + tid; i < V; i += 256) {
            float y = rowp[i];
            if (y >= YTH) {
                int p = atomicAdd(&lcnt, 1);
                if (p < SEGCAP) { Av[p] = y; Ai[p] = i; }
            }
        }
    }
#undef PUSH4
    __syncthreads();

    const int cnt = lcnt;
    {   // publish segment via sc1 stores (write-through the non-coherent L2)
        float* cyr = cy + ((size_t)row * SLICES + sl) * SEGCAP;
        int*   cir = ci + ((size_t)row * SLICES + sl) * SEGCAP;
        for (int p = tid; p < min(cnt, SEGCAP); p += NTH) {
            ST_SC1(&cyr[p], Av[p]);
            ST_SC1(&cir[p], Ai[p]);
        }
        if (tid == 0) ST_SC1(&scnt[row * SLICES + sl], cnt);  // >SEGCAP => ovfl
    }

    // ---- handoff: last-arriving block of this row runs the selection ----
    // __syncthreads drains vmcnt(0): all sc1 stores are ACKed at the device
    // coherence point before the ticket RMW issues. NO fences (R12 lesson:
    // threadfence = full-L2 wbl2/inv on gfx950, ~290 us across 2048 blocks).
    __syncthreads();
    if (tid == 0)
        is_last_sh = (__hip_atomic_fetch_add(&done_ctr[row], 1,
                          __ATOMIC_RELAXED, __HIP_MEMORY_SCOPE_AGENT)
                      == SLICES - 1);
    __syncthreads();
    if (!is_last_sh) return;         // block-uniform

    // ================= selection phase (256 threads) =================
    const int k_in = *topk_p;

    if (tid == 0) { hi_cnt = 0; cpos = 0; scount = 0; }
    if (tid < 64) {
        int c = (tid < SLICES) ? LD_SC1(&scnt[row * SLICES + tid]) : 0;
        int bad = (tid < SLICES) && (c > SEGCAP);
        int acc = min(c, SEGCAP);
#pragma unroll
        for (int off = 1; off < SLICES; off <<= 1) {
            int o = __shfl_up(acc, off, 64);
            if (tid >= off) acc += o;
        }
        if (tid < SLICES) segoff[tid + 1] = acc;
        if (tid == 0) segoff[0] = 0;
        unsigned long long bm = __ballot(bad);
        if (tid == 0) bad_sh = (bm != 0ULL);
    }
    __syncthreads();

    const int M_all = segoff[SLICES];
    int M;
    if (!bad_sh && M_all >= k_in && M_all <= MSORT) {
        {   // stage candidates: wave wv handles segments wv, wv+4, wv+8, wv+12
            const int wv = tid >> 6;
            for (int s = wv; s < SLICES; s += 4) {
                const int off = segoff[s];
                const int c   = segoff[s + 1] - off;
                if (lane < c) {
                    const size_t gbase = ((size_t)row * SLICES + s) * SEGCAP + lane;
                    Sv[off + lane] = LD_SC1(&cy[gbase]) / TEMP;
                    Si[off + lane] = LD_SC1(&ci[gbase]);
                }
            }
        }
        __syncthreads();
        {   // count high-tier candidates
            const int rounds = (M_all + NTH - 1) / NTH;
            for (int rd = 0; rd < rounds; ++rd) {
                const int t = rd * NTH + tid;
                bool pred = (t < M_all) && (Sv[t] >= XTH2);
                unsigned long long bm = __ballot(pred);
                if (lane == 0 && bm) atomicAdd(&hi_cnt, (int)__popcll(bm));
            }
        }
        __syncthreads();
        const float thr = (hi_cnt >= k_in) ? XTH2 : -1e38f;
        {   // compact survivors into Av/Ai (order canonicalized by rank sort)
            const int rounds = (M_all + NTH - 1) / NTH;
            for (int rd = 0; rd < rounds; ++rd) {
                const int t = rd * NTH + tid;
                bool pred = (t < M_all) && (Sv[t] >= thr);
                unsigned long long bm = __ballot(pred);
                if (bm) {
                    int fl = (int)__ffsll(bm) - 1;
                    int bs = 0;
                    if (pred && lane == fl) bs = atomicAdd(&cpos, (int)__popcll(bm));
                    bs = __shfl(bs, fl, 64);
                    if (pred) {
                        int p = bs + (int)__popcll(bm & ((1ULL << lane) - 1ULL));
                        Av[p] = Sv[t]; Ai[p] = Si[t];
                    }
                }
            }
        }
        __syncthreads();
        M = cpos;
    } else {
        // exact fallback: kth value via binary search on float key bits
        // (logits are read-only input: plain cached loads are safe)
        unsigned lo = 0;
        for (int bit = 31; bit >= 0; --bit) {
            unsigned tb = lo | (1u << bit);
            int local = 0;
            for (int i = tid; i < V; i += NTH) local += (fkey(rowp[i]) >= tb);
            if (tid == 0) cnt_sh = 0;
            __syncthreads();
            atomicAdd(&cnt_sh, local);
            __syncthreads();
            if (cnt_sh >= k_in) lo = tb;
            __syncthreads();
        }
        for (int i = tid; i < V; i += NTH) {
            float y = rowp[i];
            if (fkey(y) >= lo) {
                int p = atomicAdd(&scount, 1);
                if (p < MSORT) { Av[p] = y / TEMP; Ai[p] = i; }
            }
        }
        __syncthreads();
        M = min(scount, MSORT);
    }
    if (tid == 0) M_sh = M;
    __syncthreads();
    M = M_sh;

    // pad to multiple of 4 with sentinels (branch-free unrolled inner loop)
    const int Mpad = (M + 3) & ~3;
    for (int t = M + tid; t < Mpad; t += NTH) { Av[t] = -1e38f; Ai[t] = 0x7fffffff; }
    __syncthreads();

    // rank sort: x desc, tie idx asc (== argsort(-x)); writes into Sv/Si
    for (int t = tid; t < M; t += NTH) {
        const float v = Av[t]; const int ix = Ai[t];
        int r = 0;
        for (int j = 0; j < Mpad; j += 4) {
            float v0 = Av[j],     v1 = Av[j + 1];
            float v2 = Av[j + 2], v3 = Av[j + 3];
            int   i0 = Ai[j],     i1 = Ai[j + 1];
            int   i2 = Ai[j + 2], i3 = Ai[j + 3];
            r += (v0 > v || (v0 == v && i0 < ix));
            r += (v1 > v || (v1 == v && i1 < ix));
            r += (v2 > v || (v2 == v && i2 < ix));
            r += (v3 > v || (v3 == v && i3 < ix));
        }
        Sv[r] = v; Si[r] = ix;
    }
    __syncthreads();

    // ---- decide fast (wave-0, Kp <= 128) vs slow tail ----
    if (tid < 64) {
        int kk = (M > 0) ? min(max(k_in, 1), M) : 0;
        float kth = (M > 0) ? Sv[kk - 1] : 0.0f;
        int j0 = min(kk + lane, MSORT - 1);
        int j1 = min(kk + 64 + lane, MSORT - 1);
        bool t0 = (M > 0) && (kk + lane < M)      && (Sv[j0] == kth);
        bool t1 = (M > 0) && (kk + 64 + lane < M) && (Sv[j1] == kth);
        int cnt2 = (int)__popcll(__ballot(t0)) + (int)__popcll(__ballot(t1));
        if (lane == 0) {
            Kp_sh = kk + cnt2;
            fast_sh = (M > 0) && (Kp_sh <= 128);
        }
    }
    __syncthreads();

    if (fast_sh) {
        // ================= wave-0 barrier-free tail (verbatim R11) ==========
        if (tid < 64) {
            const int Kp = Kp_sh;
            const int e0 = lane, e1 = lane + 64;
            const float mm = Sv[0];
            float se0 = (e0 < Kp) ? expf(Sv[e0] - mm) : 0.0f;
            float se1 = (e1 < Kp) ? expf(Sv[e1] - mm) : 0.0f;

            const float sum1 = wsum(se0 + se1);
            float q0 = se0 / sum1, q1 = se1 / sum1;

            // inclusive cdf over element order [0..Kp)
            float s0 = wscan(q0, lane);
            float T0 = __shfl(s0, 63, 64);
            float s1 = wscan(q1, lane) + T0;

            float prev0 = __shfl_up(s0, 1, 64);                 // Q[e0-1]
            float prev1 = __shfl_up(s1, 1, 64);
            if (lane == 0) prev1 = T0;                          // Q[63]
            bool c0 = (e0 >= 1) && (e0 < Kp) && (prev0 <= TOPP);
            bool c1 = (e1 < Kp) && (prev1 <= TOPP);
            const int L = 1 + (int)__popcll(__ballot(c0)) + (int)__popcll(__ballot(c1));

            const float sum2 = wsum(((e0 < L) ? se0 : 0.0f) + ((e1 < L) ? se1 : 0.0f));
            float p0 = se0 / sum2, p1 = se1 / sum2;
            int i0 = (e0 < L) ? Si[e0] : 0x7fffffff;
            int i1 = (e1 < L) ? Si[e1] : 0x7fffffff;

            // pad Si[L..Lpad) with INT_MAX for the x4-unrolled rank loop
            const int Lpad = (L + 3) & ~3;
            if (lane < Lpad - L) Si[L + lane] = 0x7fffffff;
            __builtin_amdgcn_wave_barrier();

            int r0 = 0, r1 = 0;
            for (int j = 0; j < Lpad; j += 4) {
                int g0 = Si[j], g1 = Si[j + 1], g2 = Si[j + 2], g3 = Si[j + 3];
                r0 += (g0 < i0) + (g1 < i0) + (g2 < i0) + (g3 < i0);
                r1 += (g0 < i1) + (g1 < i1) + (g2 < i1) + (g3 < i1);
            }
            if (e0 < L) { Av[r0] = p0; Ai[r0] = i0; }
            if (e1 < L) { Av[r1] = p1; Ai[r1] = i1; }
            __builtin_amdgcn_wave_barrier();

            // vocab-order cdf + unique crossing
            float g0v = (e0 < L) ? Av[e0] : 0.0f;
            float g1v = (e1 < L) ? Av[e1] : 0.0f;
            int   vi0 = (e0 < L) ? Ai[e0] : 0;
            int   vi1 = (e1 < L) ? Ai[e1] : 0;
            float C0 = wscan(g0v, lane);
            float TT = __shfl(C0, 63, 64);
            float C1 = wscan(g1v, lane) + TT;
            float pc0 = __shfl_up(C0, 1, 64);
            float pc1 = __shfl_up(C1, 1, 64);
            if (lane == 0) pc1 = TT;
            const float uu = uvec[row];
            bool f0 = (e0 < L) && (C0 > uu) && (e0 == 0 || pc0 <= uu);
            bool f1 = (e1 < L) && (C1 > uu) && (pc1 <= uu);
            int ans = V;
            if (f0) ans = vi0;
            if (f1) ans = vi1;
#pragma unroll
            for (int off = 32; off > 0; off >>= 1)
                ans = min(ans, __shfl_xor(ans, off, 64));
            if (lane == 0) out[row] = ans;
        }
        return;
    }

    // ============ slow tail (Kp > 128 / M == 0): serial-exact, never fires ==
    if (tid == 0) {
        int ans = V;
        if (M > 0) {
            const int kk = min(max(k_in, 1), M);
            const float kth = Sv[kk - 1];
            int Kp = kk;
            for (int t = kk; t < M; ++t) Kp += (Sv[t] == kth);
            const float mm = Sv[0];
            float sum1 = 0.0f;
            for (int t = 0; t < Kp; ++t) sum1 += expf(Sv[t] - mm);
            // L = 1 + #{ t in [1,Kp) : cdf[t-1] <= TOPP }
            int L = 1;
            float pref = 0.0f;
            for (int t = 1; t < Kp; ++t) {
                pref += expf(Sv[t - 1] - mm) / sum1;
                L += (pref <= TOPP);
            }
            float sum2 = 0.0f;
            for (int t = 0; t < L; ++t) sum2 += expf(Sv[t] - mm);
            const float uu = uvec[row];
            // vocab-order traversal via repeated min-extraction; first cdf>u
            int last = -1;
            float csum = 0.0f;
            for (int step = 0; step < L; ++step) {
                int mn = 0x7fffffff, mt = -1;
                for (int t = 0; t < L; ++t) {
                    int ix = Si[t];
                    if (ix > last && ix < mn) { mn = ix; mt = t; }
                }
                last = mn;
                csum += expf(Sv[mt] - mm) / sum2;
                if (csum > uu) { ans = mn; break; }
            }
        }
        out[row] = ans;
    }
}

extern "C" void kernel_launch(void* const* d_in, const int* in_sizes, int n_in,
                              void* d_out, int out_size, void* d_ws, size_t ws_size,
                              hipStream_t stream) {
    const float* logits = (const float*)d_in[0];
    const float* u      = (const float*)d_in[1];
    const int*   topk   = (const int*)d_in[2];
    int*         out    = (int*)d_out;

    const int B = out_size;              // 128 rows
    const int V = in_sizes[0] / B;       // 128000

    // ws layout: done[B] | scnt[B*SLICES] | cy[B*SLICES*SEGCAP f32] | ci[i32]
    const size_t n_scnt = (size_t)B * SLICES;
    const size_t n_seg  = (size_t)B * SLICES * SEGCAP;
    int*   done = (int*)d_ws;
    int*   scnt = done + B;
    float* cy   = (float*)(scnt + n_scnt);
    int*   ci   = (int*)(cy + n_seg);

    (void)hipMemsetAsync(done, 0, (size_t)B * sizeof(int), stream);
    fused_kernel<<<B * SLICES, NTH, 0, stream>>>(logits, u, topk,
                                                 done, scnt, cy, ci, out, V);
}

// Round 3
// 103.894 us; speedup vs baseline: 3.1530x; 1.0370x over previous
//
#include <hip/hip_runtime.h>
#include <math.h>

// Sampler: temperature 0.8, top-k (k=50 input), top-p 0.9, inverse-CDF
// multinomial. B=128 rows, V=128000, fp32 logits -> int32 ids.
//
// R14: back to the two-kernel R11 structure (fusion is structurally a wash:
// a row's selection can't start before its last slice anyway, and R13 showed
// the memset dispatch + sc1 handoff costs >= the select launch it saves).
// Changes vs R11:
//  - scan publishes per-slice hi-tier counts shi[] (y/TEMP >= XTH2 over the
//    stored candidates -- bit-identical fp expression to select's old pass),
//    so select knows the threshold before touching candidate data.
//  - candidates packed as int2 (y-bits, idx): one 8 B load per candidate.
//  - select runs 256 threads (was 1024); staging+compaction fused into one
//    pass; rank sort / tie-detect / wave-0 barrier-free tail verbatim R11.
//  - slow tail serial-exact on tid0 (never fires: Kp<=128 on this data);
//    exact fallback (segment overflow / total < k) kept at 256 threads.
// No fences, no device-scope atomics, no memset (R12/R13 lessons).

#define SLICES   16
#define SEGCAP   64
#define MSORT    1024
#define NTH      256

__device__ __forceinline__ unsigned fkey(float y) {
    unsigned b = __float_as_uint(y);
    return (b & 0x80000000u) ? ~b : (b | 0x80000000u);  // y asc -> key asc
}

// wave-wide (64-lane) helpers, no barriers
__device__ __forceinline__ float wsum(float v) {
#pragma unroll
    for (int off = 32; off > 0; off >>= 1) v += __shfl_xor(v, off, 64);
    return v;
}
__device__ __forceinline__ float wscan(float v, int lane) {
#pragma unroll
    for (int off = 1; off < 64; off <<= 1) {
        float o = __shfl_up(v, off, 64);
        if (lane >= off) v += o;
    }
    return v;
}

// ---------------- Kernel 1: interleaved full-device candidate scan ----------
__global__ __launch_bounds__(256)
void scan_kernel(const float* __restrict__ logits, int V,
                 int* __restrict__ scnt, int* __restrict__ shi,
                 int2* __restrict__ cpair)
{
    constexpr float YTH  = 11.2f;   // x = 14.0
    constexpr float TEMP = 0.8f;
    constexpr float XTH2 = 16.0f;   // two-tier threshold in x-space
    __shared__ float lcy[SEGCAP];
    __shared__ int   lci[SEGCAP];
    __shared__ int   lcnt, lhic;

    const int tid = threadIdx.x;
    const int row = blockIdx.x / SLICES;
    const int sl  = blockIdx.x % SLICES;
    if (tid == 0) { lcnt = 0; lhic = 0; }
    __syncthreads();

    const float* rowp = logits + (size_t)row * (size_t)V;
    const float4* rp4 = (const float4*)rowp;
    const int n4   = V >> 2;
    const int base = sl * 256 + tid;    // float4 index, stride 4096 per j

#define PUSH4(vv, i4)                                                            \
    {                                                                            \
        float _m = fmaxf(fmaxf((vv).x, (vv).y), fmaxf((vv).z, (vv).w));          \
        if (_m >= YTH) {                                                         \
            if ((vv).x >= YTH) { int _p = atomicAdd(&lcnt, 1);                   \
                if (_p < SEGCAP) { lcy[_p] = (vv).x; lci[_p] = (i4) * 4;     } } \
            if ((vv).y >= YTH) { int _p = atomicAdd(&lcnt, 1);                   \
                if (_p < SEGCAP) { lcy[_p] = (vv).y; lci[_p] = (i4) * 4 + 1; } } \
            if ((vv).z >= YTH) { int _p = atomicAdd(&lcnt, 1);                   \
                if (_p < SEGCAP) { lcy[_p] = (vv).z; lci[_p] = (i4) * 4 + 2; } } \
            if ((vv).w >= YTH) { int _p = atomicAdd(&lcnt, 1);                   \
                if (_p < SEGCAP) { lcy[_p] = (vv).w; lci[_p] = (i4) * 4 + 3; } } \
        }                                                                        \
    }

    if (sl * 256 + 255 + 7 * 4096 < n4) {
        // fast path: 8 unconditional back-to-back loads (full MLP)
        float4 a0 = rp4[base];
        float4 a1 = rp4[base + 4096];
        float4 a2 = rp4[base + 8192];
        float4 a3 = rp4[base + 12288];
        float4 a4 = rp4[base + 16384];
        float4 a5 = rp4[base + 20480];
        float4 a6 = rp4[base + 24576];
        float4 a7 = rp4[base + 28672];
        PUSH4(a0, base);
        PUSH4(a1, base + 4096);
        PUSH4(a2, base + 8192);
        PUSH4(a3, base + 12288);
        PUSH4(a4, base + 16384);
        PUSH4(a5, base + 20480);
        PUSH4(a6, base + 24576);
        PUSH4(a7, base + 28672);
    } else {
        // edge slices: clamped branch-free loads, validity-flagged pushes
        const int nc = n4 - 1;
        int i0 = base,          c0 = min(i0, nc);
        int i1 = base + 4096,   c1 = min(i1, nc);
        int i2 = base + 8192,   c2 = min(i2, nc);
        int i3 = base + 12288,  c3 = min(i3, nc);
        int i4_ = base + 16384, c4 = min(i4_, nc);
        int i5 = base + 20480,  c5 = min(i5, nc);
        int i6 = base + 24576,  c6 = min(i6, nc);
        int i7 = base + 28672,  c7 = min(i7, nc);
        float4 a0 = rp4[c0];
        float4 a1 = rp4[c1];
        float4 a2 = rp4[c2];
        float4 a3 = rp4[c3];
        float4 a4 = rp4[c4];
        float4 a5 = rp4[c5];
        float4 a6 = rp4[c6];
        float4 a7 = rp4[c7];
        if (i0 < n4) PUSH4(a0, i0);
        if (i1 < n4) PUSH4(a1, i1);
        if (i2 < n4) PUSH4(a2, i2);
        if (i3 < n4) PUSH4(a3, i3);
        if (i4_ < n4) PUSH4(a4, i4_);
        if (i5 < n4) PUSH4(a5, i5);
        if (i6 < n4) PUSH4(a6, i6);
        if (i7 < n4) PUSH4(a7, i7);
    }
    // general-V coverage beyond 32768 float4/row (empty for V=128000)
    for (int i = SLICES * 256 * 8 + sl * 256 + tid; i < n4; i += SLICES * 256) {
        float4 a = rp4[i];
        PUSH4(a, i);
    }
    if (sl == SLICES - 1) {   // scalar tail if V % 4 != 0
        for (int i = (n4 << 2) + tid; i < V; i += 256) {
            float y = rowp[i];
            if (y >= YTH) {
                int p = atomicAdd(&lcnt, 1);
                if (p < SEGCAP) { lcy[p] = y; lci[p] = i; }
            }
        }
    }
#undef PUSH4
    __syncthreads();

    const int cnt = lcnt;
    const int cs  = min(cnt, SEGCAP);
    int2* cpr = cpair + ((size_t)row * SLICES + sl) * SEGCAP;
    for (int p = tid; p < cs; p += 256) {
        const float y = lcy[p];
        int2 pr; pr.x = __float_as_int(y); pr.y = lci[p];
        cpr[p] = pr;
        // hi-tier count: same fp expression select will use (bit-identical)
        if (y / TEMP >= XTH2) atomicAdd(&lhic, 1);
    }
    __syncthreads();
    if (tid == 0) {
        scnt[row * SLICES + sl] = cnt;   // cnt > SEGCAP => overflow
        shi [row * SLICES + sl] = lhic;
    }
}

// ---------------- Kernel 2: per-row selection + sampling (256 thr) ----------
__global__ __launch_bounds__(256)
void select_kernel(const float* __restrict__ logits,
                   const float* __restrict__ uvec,
                   const int* __restrict__ topk_p,
                   const int* __restrict__ scnt,
                   const int* __restrict__ shi,
                   const int2* __restrict__ cpair,
                   int* __restrict__ out, int V)
{
    constexpr float TEMP = 0.8f;
    constexpr float TOPP = 0.9f;
    constexpr float XTH2 = 16.0f;

    __shared__ float Sv[MSORT];
    __shared__ int   Si[MSORT];
    __shared__ float Av[MSORT];
    __shared__ int   Ai[MSORT];
    __shared__ int   segoff[SLICES + 1];
    __shared__ float thr_sh;
    __shared__ int   cpos, scount, cnt_sh, M_sh, Kp_sh, fast_sh, bad_sh;

    const int tid  = threadIdx.x;
    const int lane = tid & 63;
    const int row  = blockIdx.x;
    const int k_in = *topk_p;
    const float* rowp = logits + (size_t)row * (size_t)V;

    if (tid == 0) { cpos = 0; scount = 0; }
    if (tid < 64) {
        int c = (tid < SLICES) ? scnt[row * SLICES + tid] : 0;
        int h = (tid < SLICES) ? shi [row * SLICES + tid] : 0;
        int bad = (tid < SLICES) && (c > SEGCAP);
        int acc = min(c, SEGCAP);
#pragma unroll
        for (int off = 1; off < SLICES; off <<= 1) {
            int o = __shfl_up(acc, off, 64);
            if (tid >= off) acc += o;
        }
        if (tid < SLICES) segoff[tid + 1] = acc;
        if (tid == 0) segoff[0] = 0;
#pragma unroll
        for (int off = 32; off > 0; off >>= 1) h += __shfl_xor(h, off, 64);
        unsigned long long bm = __ballot(bad);
        if (tid == 0) {
            bad_sh = (bm != 0ULL);
            thr_sh = (h >= k_in) ? XTH2 : -1e38f;   // hi-tier decision up front
        }
    }
    __syncthreads();

    const int M_all = segoff[SLICES];
    int M;
    if (!bad_sh && M_all >= k_in && M_all <= MSORT) {
        // fused stage+compact, one pass: wave wv owns segments wv, wv+4, ...
        const float thr = thr_sh;
        const int wv = tid >> 6;
        for (int s = wv; s < SLICES; s += 4) {
            const int c = segoff[s + 1] - segoff[s];
            float x = -1e38f; int ix = 0;
            bool pred = false;
            if (lane < c) {
                int2 pr = cpair[((size_t)row * SLICES + s) * SEGCAP + lane];
                x = __int_as_float(pr.x) / TEMP;
                ix = pr.y;
                pred = (x >= thr);
            }
            unsigned long long bm = __ballot(pred);
            if (bm) {
                int fl = (int)__ffsll(bm) - 1;
                int bs = 0;
                if (pred && lane == fl) bs = atomicAdd(&cpos, (int)__popcll(bm));
                bs = __shfl(bs, fl, 64);
                if (pred) {
                    int p = bs + (int)__popcll(bm & ((1ULL << lane) - 1ULL));
                    Av[p] = x; Ai[p] = ix;
                }
            }
        }
        __syncthreads();
        M = cpos;
    } else {
        // exact fallback: kth value via binary search on float key bits
        unsigned lo = 0;
        for (int bit = 31; bit >= 0; --bit) {
            unsigned tb = lo | (1u << bit);
            int local = 0;
            for (int i = tid; i < V; i += NTH) local += (fkey(rowp[i]) >= tb);
            if (tid == 0) cnt_sh = 0;
            __syncthreads();
            atomicAdd(&cnt_sh, local);
            __syncthreads();
            if (cnt_sh >= k_in) lo = tb;
            __syncthreads();
        }
        for (int i = tid; i < V; i += NTH) {
            float y = rowp[i];
            if (fkey(y) >= lo) {
                int p = atomicAdd(&scount, 1);
                if (p < MSORT) { Av[p] = y / TEMP; Ai[p] = i; }
            }
        }
        __syncthreads();
        M = min(scount, MSORT);
    }
    if (tid == 0) M_sh = M;
    __syncthreads();
    M = M_sh;

    // pad to multiple of 4 with sentinels (branch-free unrolled inner loop)
    const int Mpad = (M + 3) & ~3;
    for (int t = M + tid; t < Mpad; t += NTH) { Av[t] = -1e38f; Ai[t] = 0x7fffffff; }
    __syncthreads();

    // rank sort: x desc, tie idx asc (== argsort(-x)); writes into Sv/Si
    for (int t = tid; t < M; t += NTH) {
        const float v = Av[t]; const int ix = Ai[t];
        int r = 0;
        for (int j = 0; j < Mpad; j += 4) {
            float v0 = Av[j],     v1 = Av[j + 1];
            float v2 = Av[j + 2], v3 = Av[j + 3];
            int   i0 = Ai[j],     i1 = Ai[j + 1];
            int   i2 = Ai[j + 2], i3 = Ai[j + 3];
            r += (v0 > v || (v0 == v && i0 < ix));
            r += (v1 > v || (v1 == v && i1 < ix));
            r += (v2 > v || (v2 == v && i2 < ix));
            r += (v3 > v || (v3 == v && i3 < ix));
        }
        Sv[r] = v; Si[r] = ix;
    }
    __syncthreads();

    // ---- decide fast (wave-0, Kp <= 128) vs slow tail ----
    if (tid < 64) {
        int kk = (M > 0) ? min(max(k_in, 1), M) : 0;
        float kth = (M > 0) ? Sv[kk - 1] : 0.0f;
        int j0 = min(kk + lane, MSORT - 1);
        int j1 = min(kk + 64 + lane, MSORT - 1);
        bool t0 = (M > 0) && (kk + lane < M)      && (Sv[j0] == kth);
        bool t1 = (M > 0) && (kk + 64 + lane < M) && (Sv[j1] == kth);
        int cnt2 = (int)__popcll(__ballot(t0)) + (int)__popcll(__ballot(t1));
        if (lane == 0) {
            Kp_sh = kk + cnt2;
            fast_sh = (M > 0) && (Kp_sh <= 128);
        }
    }
    __syncthreads();

    if (fast_sh) {
        // ================= wave-0 barrier-free tail (verbatim R11) ==========
        if (tid < 64) {
            const int Kp = Kp_sh;
            const int e0 = lane, e1 = lane + 64;
            const float mm = Sv[0];
            float se0 = (e0 < Kp) ? expf(Sv[e0] - mm) : 0.0f;
            float se1 = (e1 < Kp) ? expf(Sv[e1] - mm) : 0.0f;

            const float sum1 = wsum(se0 + se1);
            float q0 = se0 / sum1, q1 = se1 / sum1;

            // inclusive cdf over element order [0..Kp)
            float s0 = wscan(q0, lane);
            float T0 = __shfl(s0, 63, 64);
            float s1 = wscan(q1, lane) + T0;

            float prev0 = __shfl_up(s0, 1, 64);                 // Q[e0-1]
            float prev1 = __shfl_up(s1, 1, 64);
            if (lane == 0) prev1 = T0;                          // Q[63]
            bool c0 = (e0 >= 1) && (e0 < Kp) && (prev0 <= TOPP);
            bool c1 = (e1 < Kp) && (prev1 <= TOPP);
            const int L = 1 + (int)__popcll(__ballot(c0)) + (int)__popcll(__ballot(c1));

            const float sum2 = wsum(((e0 < L) ? se0 : 0.0f) + ((e1 < L) ? se1 : 0.0f));
            float p0 = se0 / sum2, p1 = se1 / sum2;
            int i0 = (e0 < L) ? Si[e0] : 0x7fffffff;
            int i1 = (e1 < L) ? Si[e1] : 0x7fffffff;

            // pad Si[L..Lpad) with INT_MAX for the x4-unrolled rank loop
            const int Lpad = (L + 3) & ~3;
            if (lane < Lpad - L) Si[L + lane] = 0x7fffffff;
            __builtin_amdgcn_wave_barrier();

            int r0 = 0, r1 = 0;
            for (int j = 0; j < Lpad; j += 4) {
                int g0 = Si[j], g1 = Si[j + 1], g2 = Si[j + 2], g3 = Si[j + 3];
                r0 += (g0 < i0) + (g1 < i0) + (g2 < i0) + (g3 < i0);
                r1 += (g0 < i1) + (g1 < i1) + (g2 < i1) + (g3 < i1);
            }
            if (e0 < L) { Av[r0] = p0; Ai[r0] = i0; }
            if (e1 < L) { Av[r1] = p1; Ai[r1] = i1; }
            __builtin_amdgcn_wave_barrier();

            // vocab-order cdf + unique crossing
            float g0v = (e0 < L) ? Av[e0] : 0.0f;
            float g1v = (e1 < L) ? Av[e1] : 0.0f;
            int   vi0 = (e0 < L) ? Ai[e0] : 0;
            int   vi1 = (e1 < L) ? Ai[e1] : 0;
            float C0 = wscan(g0v, lane);
            float TT = __shfl(C0, 63, 64);
            float C1 = wscan(g1v, lane) + TT;
            float pc0 = __shfl_up(C0, 1, 64);
            float pc1 = __shfl_up(C1, 1, 64);
            if (lane == 0) pc1 = TT;
            const float uu = uvec[row];
            bool f0 = (e0 < L) && (C0 > uu) && (e0 == 0 || pc0 <= uu);
            bool f1 = (e1 < L) && (C1 > uu) && (pc1 <= uu);
            int ans = V;
            if (f0) ans = vi0;
            if (f1) ans = vi1;
#pragma unroll
            for (int off = 32; off > 0; off >>= 1)
                ans = min(ans, __shfl_xor(ans, off, 64));
            if (lane == 0) out[row] = ans;
        }
        return;
    }

    // ============ slow tail (Kp > 128 / M == 0): serial-exact, never fires ==
    if (tid == 0) {
        int ans = V;
        if (M > 0) {
            const int kk = min(max(k_in, 1), M);
            const float kth = Sv[kk - 1];
            int Kp = kk;
            for (int t = kk; t < M; ++t) Kp += (Sv[t] == kth);
            const float mm = Sv[0];
            float sum1 = 0.0f;
            for (int t = 0; t < Kp; ++t) sum1 += expf(Sv[t] - mm);
            // L = 1 + #{ t in [1,Kp) : cdf[t-1] <= TOPP }
            int L = 1;
            float pref = 0.0f;
            for (int t = 1; t < Kp; ++t) {
                pref += expf(Sv[t - 1] - mm) / sum1;
                L += (pref <= TOPP);
            }
            float sum2 = 0.0f;
            for (int t = 0; t < L; ++t) sum2 += expf(Sv[t] - mm);
            const float uu = uvec[row];
            // vocab-order traversal via repeated min-extraction; first cdf>u
            int last = -1;
            float csum = 0.0f;
            for (int step = 0; step < L; ++step) {
                int mn = 0x7fffffff, mt = -1;
                for (int t = 0; t < L; ++t) {
                    int ix = Si[t];
                    if (ix > last && ix < mn) { mn = ix; mt = t; }
                }
                last = mn;
                csum += expf(Sv[mt] - mm) / sum2;
                if (csum > uu) { ans = mn; break; }
            }
        }
        out[row] = ans;
    }
}

extern "C" void kernel_launch(void* const* d_in, const int* in_sizes, int n_in,
                              void* d_out, int out_size, void* d_ws, size_t ws_size,
                              hipStream_t stream) {
    const float* logits = (const float*)d_in[0];
    const float* u      = (const float*)d_in[1];
    const int*   topk   = (const int*)d_in[2];
    int*         out    = (int*)d_out;

    const int B = out_size;              // 128 rows
    const int V = in_sizes[0] / B;       // 128000

    // ws layout: scnt[B*S] | shi[B*S] | cpair[B*S*SEGCAP int2]
    const size_t n_s = (size_t)B * SLICES;
    int*  scnt  = (int*)d_ws;
    int*  shi   = scnt + n_s;
    int2* cpair = (int2*)(shi + n_s);    // 16 KB offset, 8 B aligned

    scan_kernel<<<B * SLICES, NTH, 0, stream>>>(logits, V, scnt, shi, cpair);
    select_kernel<<<B, NTH, 0, stream>>>(logits, u, topk, scnt, shi, cpair,
                                         out, V);
}

// Round 4
// 100.777 us; speedup vs baseline: 3.2505x; 1.0309x over previous
//
#include <hip/hip_runtime.h>
#include <math.h>

// Sampler: temperature 0.8, top-k (k=50 input), top-p 0.9, inverse-CDF
// multinomial. B=128 rows, V=128000, fp32 logits -> int32 ids.
//
// R15: hybrid of the proven parts. R14's 256-thread select REGRESSED
// (+2.6 us vs R11): the rank sort is the serial core -- at 256 threads each
// thread owns 2 candidates (2x critical path) and 4x fewer waves hide the
// gather latency. So: scan kernel stays R14 (publishes per-slice hi-tier
// counts shi[] + int2-packed candidates), select goes back to 1024 threads
// (R11 width) keeping only the width-independent R14 wins:
//  - threshold decided up front from shi[] (drops R11's ballot-count pass),
//  - stage+compact fused in one pass: wave w owns segment w (16 waves <->
//    16 segments, SEGCAP=64=wave width), one 8 B int2 load per candidate,
//  - rank sort / tie-detect / wave-0 barrier-free tail verbatim R11.
// Slow tail serial-exact on tid0 (never fires: Kp<=128 on this data);
// exact fallback (segment overflow / total < k) kept at 1024 threads.
// No fences, no device-scope atomics, no memset (R12/R13 lessons).

#define SLICES   16
#define SEGCAP   64
#define MSORT    1024
#define NTH      256     // scan block size
#define NSEL     1024    // select block size

__device__ __forceinline__ unsigned fkey(float y) {
    unsigned b = __float_as_uint(y);
    return (b & 0x80000000u) ? ~b : (b | 0x80000000u);  // y asc -> key asc
}

// wave-wide (64-lane) helpers, no barriers
__device__ __forceinline__ float wsum(float v) {
#pragma unroll
    for (int off = 32; off > 0; off >>= 1) v += __shfl_xor(v, off, 64);
    return v;
}
__device__ __forceinline__ float wscan(float v, int lane) {
#pragma unroll
    for (int off = 1; off < 64; off <<= 1) {
        float o = __shfl_up(v, off, 64);
        if (lane >= off) v += o;
    }
    return v;
}

// ---------------- Kernel 1: interleaved full-device candidate scan ----------
__global__ __launch_bounds__(256)
void scan_kernel(const float* __restrict__ logits, int V,
                 int* __restrict__ scnt, int* __restrict__ shi,
                 int2* __restrict__ cpair)
{
    constexpr float YTH  = 11.2f;   // x = 14.0
    constexpr float TEMP = 0.8f;
    constexpr float XTH2 = 16.0f;   // two-tier threshold in x-space
    __shared__ float lcy[SEGCAP];
    __shared__ int   lci[SEGCAP];
    __shared__ int   lcnt, lhic;

    const int tid = threadIdx.x;
    const int row = blockIdx.x / SLICES;
    const int sl  = blockIdx.x % SLICES;
    if (tid == 0) { lcnt = 0; lhic = 0; }
    __syncthreads();

    const float* rowp = logits + (size_t)row * (size_t)V;
    const float4* rp4 = (const float4*)rowp;
    const int n4   = V >> 2;
    const int base = sl * 256 + tid;    // float4 index, stride 4096 per j

#define PUSH4(vv, i4)                                                            \
    {                                                                            \
        float _m = fmaxf(fmaxf((vv).x, (vv).y), fmaxf((vv).z, (vv).w));          \
        if (_m >= YTH) {                                                         \
            if ((vv).x >= YTH) { int _p = atomicAdd(&lcnt, 1);                   \
                if (_p < SEGCAP) { lcy[_p] = (vv).x; lci[_p] = (i4) * 4;     } } \
            if ((vv).y >= YTH) { int _p = atomicAdd(&lcnt, 1);                   \
                if (_p < SEGCAP) { lcy[_p] = (vv).y; lci[_p] = (i4) * 4 + 1; } } \
            if ((vv).z >= YTH) { int _p = atomicAdd(&lcnt, 1);                   \
                if (_p < SEGCAP) { lcy[_p] = (vv).z; lci[_p] = (i4) * 4 + 2; } } \
            if ((vv).w >= YTH) { int _p = atomicAdd(&lcnt, 1);                   \
                if (_p < SEGCAP) { lcy[_p] = (vv).w; lci[_p] = (i4) * 4 + 3; } } \
        }                                                                        \
    }

    if (sl * 256 + 255 + 7 * 4096 < n4) {
        // fast path: 8 unconditional back-to-back loads (full MLP)
        float4 a0 = rp4[base];
        float4 a1 = rp4[base + 4096];
        float4 a2 = rp4[base + 8192];
        float4 a3 = rp4[base + 12288];
        float4 a4 = rp4[base + 16384];
        float4 a5 = rp4[base + 20480];
        float4 a6 = rp4[base + 24576];
        float4 a7 = rp4[base + 28672];
        PUSH4(a0, base);
        PUSH4(a1, base + 4096);
        PUSH4(a2, base + 8192);
        PUSH4(a3, base + 12288);
        PUSH4(a4, base + 16384);
        PUSH4(a5, base + 20480);
        PUSH4(a6, base + 24576);
        PUSH4(a7, base + 28672);
    } else {
        // edge slices: clamped branch-free loads, validity-flagged pushes
        const int nc = n4 - 1;
        int i0 = base,          c0 = min(i0, nc);
        int i1 = base + 4096,   c1 = min(i1, nc);
        int i2 = base + 8192,   c2 = min(i2, nc);
        int i3 = base + 12288,  c3 = min(i3, nc);
        int i4_ = base + 16384, c4 = min(i4_, nc);
        int i5 = base + 20480,  c5 = min(i5, nc);
        int i6 = base + 24576,  c6 = min(i6, nc);
        int i7 = base + 28672,  c7 = min(i7, nc);
        float4 a0 = rp4[c0];
        float4 a1 = rp4[c1];
        float4 a2 = rp4[c2];
        float4 a3 = rp4[c3];
        float4 a4 = rp4[c4];
        float4 a5 = rp4[c5];
        float4 a6 = rp4[c6];
        float4 a7 = rp4[c7];
        if (i0 < n4) PUSH4(a0, i0);
        if (i1 < n4) PUSH4(a1, i1);
        if (i2 < n4) PUSH4(a2, i2);
        if (i3 < n4) PUSH4(a3, i3);
        if (i4_ < n4) PUSH4(a4, i4_);
        if (i5 < n4) PUSH4(a5, i5);
        if (i6 < n4) PUSH4(a6, i6);
        if (i7 < n4) PUSH4(a7, i7);
    }
    // general-V coverage beyond 32768 float4/row (empty for V=128000)
    for (int i = SLICES * 256 * 8 + sl * 256 + tid; i < n4; i += SLICES * 256) {
        float4 a = rp4[i];
        PUSH4(a, i);
    }
    if (sl == SLICES - 1) {   // scalar tail if V % 4 != 0
        for (int i = (n4 << 2) + tid; i < V; i += 256) {
            float y = rowp[i];
            if (y >= YTH) {
                int p = atomicAdd(&lcnt, 1);
                if (p < SEGCAP) { lcy[p] = y; lci[p] = i; }
            }
        }
    }
#undef PUSH4
    __syncthreads();

    const int cnt = lcnt;
    const int cs  = min(cnt, SEGCAP);
    int2* cpr = cpair + ((size_t)row * SLICES + sl) * SEGCAP;
    for (int p = tid; p < cs; p += 256) {
        const float y = lcy[p];
        int2 pr; pr.x = __float_as_int(y); pr.y = lci[p];
        cpr[p] = pr;
        // hi-tier count: same fp expression select will use (bit-identical)
        if (y / TEMP >= XTH2) atomicAdd(&lhic, 1);
    }
    __syncthreads();
    if (tid == 0) {
        scnt[row * SLICES + sl] = cnt;   // cnt > SEGCAP => overflow
        shi [row * SLICES + sl] = lhic;
    }
}

// ---------------- Kernel 2: per-row selection + sampling (1024 thr) ---------
__global__ __launch_bounds__(1024)
void select_kernel(const float* __restrict__ logits,
                   const float* __restrict__ uvec,
                   const int* __restrict__ topk_p,
                   const int* __restrict__ scnt,
                   const int* __restrict__ shi,
                   const int2* __restrict__ cpair,
                   int* __restrict__ out, int V)
{
    constexpr float TEMP = 0.8f;
    constexpr float TOPP = 0.9f;
    constexpr float XTH2 = 16.0f;

    __shared__ float Sv[MSORT];
    __shared__ int   Si[MSORT];
    __shared__ float Av[MSORT];
    __shared__ int   Ai[MSORT];
    __shared__ int   segoff[SLICES + 1];
    __shared__ float thr_sh;
    __shared__ int   cpos, scount, cnt_sh, M_sh, Kp_sh, fast_sh, bad_sh;

    const int tid  = threadIdx.x;
    const int lane = tid & 63;
    const int row  = blockIdx.x;
    const int k_in = *topk_p;
    const float* rowp = logits + (size_t)row * (size_t)V;

    if (tid == 0) { cpos = 0; scount = 0; }
    if (tid < 64) {
        int c = (tid < SLICES) ? scnt[row * SLICES + tid] : 0;
        int h = (tid < SLICES) ? shi [row * SLICES + tid] : 0;
        int bad = (tid < SLICES) && (c > SEGCAP);
        int acc = min(c, SEGCAP);
#pragma unroll
        for (int off = 1; off < SLICES; off <<= 1) {
            int o = __shfl_up(acc, off, 64);
            if (tid >= off) acc += o;
        }
        if (tid < SLICES) segoff[tid + 1] = acc;
        if (tid == 0) segoff[0] = 0;
#pragma unroll
        for (int off = 32; off > 0; off >>= 1) h += __shfl_xor(h, off, 64);
        unsigned long long bm = __ballot(bad);
        if (tid == 0) {
            bad_sh = (bm != 0ULL);
            thr_sh = (h >= k_in) ? XTH2 : -1e38f;   // hi-tier decision up front
        }
    }
    __syncthreads();

    const int M_all = segoff[SLICES];
    int M;
    if (!bad_sh && M_all >= k_in && M_all <= MSORT) {
        // fused stage+compact, one pass: wave w owns segment w (16 waves)
        const float thr = thr_sh;
        const int s = tid >> 6;
        const int c = segoff[s + 1] - segoff[s];
        float x = -1e38f; int ix = 0;
        bool pred = false;
        if (lane < c) {
            int2 pr = cpair[((size_t)row * SLICES + s) * SEGCAP + lane];
            x = __int_as_float(pr.x) / TEMP;
            ix = pr.y;
            pred = (x >= thr);
        }
        unsigned long long bm = __ballot(pred);
        if (bm) {
            int fl = (int)__ffsll(bm) - 1;
            int bs = 0;
            if (pred && lane == fl) bs = atomicAdd(&cpos, (int)__popcll(bm));
            bs = __shfl(bs, fl, 64);
            if (pred) {
                int p = bs + (int)__popcll(bm & ((1ULL << lane) - 1ULL));
                Av[p] = x; Ai[p] = ix;
            }
        }
        __syncthreads();
        M = cpos;
    } else {
        // exact fallback: kth value via binary search on float key bits
        unsigned lo = 0;
        for (int bit = 31; bit >= 0; --bit) {
            unsigned tb = lo | (1u << bit);
            int local = 0;
            for (int i = tid; i < V; i += NSEL) local += (fkey(rowp[i]) >= tb);
            if (tid == 0) cnt_sh = 0;
            __syncthreads();
            atomicAdd(&cnt_sh, local);
            __syncthreads();
            if (cnt_sh >= k_in) lo = tb;
            __syncthreads();
        }
        for (int i = tid; i < V; i += NSEL) {
            float y = rowp[i];
            if (fkey(y) >= lo) {
                int p = atomicAdd(&scount, 1);
                if (p < MSORT) { Av[p] = y / TEMP; Ai[p] = i; }
            }
        }
        __syncthreads();
        M = min(scount, MSORT);
    }
    if (tid == 0) M_sh = M;
    __syncthreads();
    M = M_sh;

    // pad to multiple of 4 with sentinels (branch-free unrolled inner loop)
    const int Mpad = (M + 3) & ~3;
    for (int t = M + tid; t < Mpad; t += NSEL) { Av[t] = -1e38f; Ai[t] = 0x7fffffff; }
    __syncthreads();

    // rank sort: x desc, tie idx asc (== argsort(-x)); writes into Sv/Si
    for (int t = tid; t < M; t += NSEL) {
        const float v = Av[t]; const int ix = Ai[t];
        int r = 0;
        for (int j = 0; j < Mpad; j += 4) {
            float v0 = Av[j],     v1 = Av[j + 1];
            float v2 = Av[j + 2], v3 = Av[j + 3];
            int   i0 = Ai[j],     i1 = Ai[j + 1];
            int   i2 = Ai[j + 2], i3 = Ai[j + 3];
            r += (v0 > v || (v0 == v && i0 < ix));
            r += (v1 > v || (v1 == v && i1 < ix));
            r += (v2 > v || (v2 == v && i2 < ix));
            r += (v3 > v || (v3 == v && i3 < ix));
        }
        Sv[r] = v; Si[r] = ix;
    }
    __syncthreads();

    // ---- decide fast (wave-0, Kp <= 128) vs slow tail ----
    if (tid < 64) {
        int kk = (M > 0) ? min(max(k_in, 1), M) : 0;
        float kth = (M > 0) ? Sv[kk - 1] : 0.0f;
        int j0 = min(kk + lane, MSORT - 1);
        int j1 = min(kk + 64 + lane, MSORT - 1);
        bool t0 = (M > 0) && (kk + lane < M)      && (Sv[j0] == kth);
        bool t1 = (M > 0) && (kk + 64 + lane < M) && (Sv[j1] == kth);
        int cnt2 = (int)__popcll(__ballot(t0)) + (int)__popcll(__ballot(t1));
        if (lane == 0) {
            Kp_sh = kk + cnt2;
            fast_sh = (M > 0) && (Kp_sh <= 128);
        }
    }
    __syncthreads();

    if (fast_sh) {
        // ================= wave-0 barrier-free tail (verbatim R11) ==========
        if (tid < 64) {
            const int Kp = Kp_sh;
            const int e0 = lane, e1 = lane + 64;
            const float mm = Sv[0];
            float se0 = (e0 < Kp) ? expf(Sv[e0] - mm) : 0.0f;
            float se1 = (e1 < Kp) ? expf(Sv[e1] - mm) : 0.0f;

            const float sum1 = wsum(se0 + se1);
            float q0 = se0 / sum1, q1 = se1 / sum1;

            // inclusive cdf over element order [0..Kp)
            float s0 = wscan(q0, lane);
            float T0 = __shfl(s0, 63, 64);
            float s1 = wscan(q1, lane) + T0;

            float prev0 = __shfl_up(s0, 1, 64);                 // Q[e0-1]
            float prev1 = __shfl_up(s1, 1, 64);
            if (lane == 0) prev1 = T0;                          // Q[63]
            bool c0 = (e0 >= 1) && (e0 < Kp) && (prev0 <= TOPP);
            bool c1 = (e1 < Kp) && (prev1 <= TOPP);
            const int L = 1 + (int)__popcll(__ballot(c0)) + (int)__popcll(__ballot(c1));

            const float sum2 = wsum(((e0 < L) ? se0 : 0.0f) + ((e1 < L) ? se1 : 0.0f));
            float p0 = se0 / sum2, p1 = se1 / sum2;
            int i0 = (e0 < L) ? Si[e0] : 0x7fffffff;
            int i1 = (e1 < L) ? Si[e1] : 0x7fffffff;

            // pad Si[L..Lpad) with INT_MAX for the x4-unrolled rank loop
            const int Lpad = (L + 3) & ~3;
            if (lane < Lpad - L) Si[L + lane] = 0x7fffffff;
            __builtin_amdgcn_wave_barrier();

            int r0 = 0, r1 = 0;
            for (int j = 0; j < Lpad; j += 4) {
                int g0 = Si[j], g1 = Si[j + 1], g2 = Si[j + 2], g3 = Si[j + 3];
                r0 += (g0 < i0) + (g1 < i0) + (g2 < i0) + (g3 < i0);
                r1 += (g0 < i1) + (g1 < i1) + (g2 < i1) + (g3 < i1);
            }
            if (e0 < L) { Av[r0] = p0; Ai[r0] = i0; }
            if (e1 < L) { Av[r1] = p1; Ai[r1] = i1; }
            __builtin_amdgcn_wave_barrier();

            // vocab-order cdf + unique crossing
            float g0v = (e0 < L) ? Av[e0] : 0.0f;
            float g1v = (e1 < L) ? Av[e1] : 0.0f;
            int   vi0 = (e0 < L) ? Ai[e0] : 0;
            int   vi1 = (e1 < L) ? Ai[e1] : 0;
            float C0 = wscan(g0v, lane);
            float TT = __shfl(C0, 63, 64);
            float C1 = wscan(g1v, lane) + TT;
            float pc0 = __shfl_up(C0, 1, 64);
            float pc1 = __shfl_up(C1, 1, 64);
            if (lane == 0) pc1 = TT;
            const float uu = uvec[row];
            bool f0 = (e0 < L) && (C0 > uu) && (e0 == 0 || pc0 <= uu);
            bool f1 = (e1 < L) && (C1 > uu) && (pc1 <= uu);
            int ans = V;
            if (f0) ans = vi0;
            if (f1) ans = vi1;
#pragma unroll
            for (int off = 32; off > 0; off >>= 1)
                ans = min(ans, __shfl_xor(ans, off, 64));
            if (lane == 0) out[row] = ans;
        }
        return;
    }

    // ============ slow tail (Kp > 128 / M == 0): serial-exact, never fires ==
    if (tid == 0) {
        int ans = V;
        if (M > 0) {
            const int kk = min(max(k_in, 1), M);
            const float kth = Sv[kk - 1];
            int Kp = kk;
            for (int t = kk; t < M; ++t) Kp += (Sv[t] == kth);
            const float mm = Sv[0];
            float sum1 = 0.0f;
            for (int t = 0; t < Kp; ++t) sum1 += expf(Sv[t] - mm);
            // L = 1 + #{ t in [1,Kp) : cdf[t-1] <= TOPP }
            int L = 1;
            float pref = 0.0f;
            for (int t = 1; t < Kp; ++t) {
                pref += expf(Sv[t - 1] - mm) / sum1;
                L += (pref <= TOPP);
            }
            float sum2 = 0.0f;
            for (int t = 0; t < L; ++t) sum2 += expf(Sv[t] - mm);
            const float uu = uvec[row];
            // vocab-order traversal via repeated min-extraction; first cdf>u
            int last = -1;
            float csum = 0.0f;
            for (int step = 0; step < L; ++step) {
                int mn = 0x7fffffff, mt = -1;
                for (int t = 0; t < L; ++t) {
                    int ix = Si[t];
                    if (ix > last && ix < mn) { mn = ix; mt = t; }
                }
                last = mn;
                csum += expf(Sv[mt] - mm) / sum2;
                if (csum > uu) { ans = mn; break; }
            }
        }
        out[row] = ans;
    }
}

extern "C" void kernel_launch(void* const* d_in, const int* in_sizes, int n_in,
                              void* d_out, int out_size, void* d_ws, size_t ws_size,
                              hipStream_t stream) {
    const float* logits = (const float*)d_in[0];
    const float* u      = (const float*)d_in[1];
    const int*   topk   = (const int*)d_in[2];
    int*         out    = (int*)d_out;

    const int B = out_size;              // 128 rows
    const int V = in_sizes[0] / B;       // 128000

    // ws layout: scnt[B*S] | shi[B*S] | cpair[B*S*SEGCAP int2]
    const size_t n_s = (size_t)B * SLICES;
    int*  scnt  = (int*)d_ws;
    int*  shi   = scnt + n_s;
    int2* cpair = (int2*)(shi + n_s);    // 16 KB offset, 8 B aligned

    scan_kernel<<<B * SLICES, NTH, 0, stream>>>(logits, V, scnt, shi, cpair);
    select_kernel<<<B, NSEL, 0, stream>>>(logits, u, topk, scnt, shi, cpair,
                                          out, V);
}